// Round 5
// baseline (272.988 us; speedup 1.0000x reference)
//
#include <hip/hip_runtime.h>
#include <stdint.h>

// T-structure as a signed permutation: for each (k,p) there is exactly one q
// with sign s such that T[k,p,q] = s. Transcribed from _TERMS.
__constant__ signed char QTAB[64] = {
    0,1,2,3,4,5,6,7,
    1,0,4,5,2,3,7,6,
    2,4,0,6,1,7,3,5,
    3,5,6,0,7,1,2,4,
    4,2,1,7,0,6,5,3,
    5,3,7,1,6,0,4,2,
    6,7,3,2,5,4,0,1,
    7,6,5,4,3,2,1,0};
__constant__ signed char SGN[64] = {
    1, 1, 1, 1,-1,-1,-1,-1,
    1, 1,-1, 1, 1,-1,-1,-1,
    1, 1, 1,-1,-1, 1, 1,-1,
    1,-1, 1, 1,-1,-1,-1, 1,
    1, 1,-1, 1, 1,-1, 1,-1,
    1,-1, 1, 1, 1, 1,-1,-1,
    1,-1,-1, 1,-1, 1, 1, 1,
    1, 1,-1, 1, 1,-1, 1, 1};

// W2[iq][m] such that out[b][m] = sum_iq x[b][iq] * W2[iq][m]  (m = o*8+k,
// iq = i*8+q). Each entry written exactly once (QTAB rows are permutations).
__global__ void clifford_prep(const float* __restrict__ weight,
                              float* __restrict__ W2) {
    int t = threadIdx.x;
    for (int e = t; e < 4096; e += 256) {
        int o = e >> 9, i = (e >> 6) & 7, k = (e >> 3) & 7, p = e & 7;
        int q = (int)QTAB[k * 8 + p];
        float s = (float)SGN[k * 8 + p];
        W2[((i * 8 + q) * 64) + (o * 8 + k)] = s * weight[(o * 8 + i) * 8 + p];
    }
}

typedef __attribute__((address_space(1))) const float gfloat;
typedef __attribute__((address_space(3))) float sfloat;

#define WAITVM8 \
    asm volatile("s_waitcnt vmcnt(8)" ::: "memory"); \
    __builtin_amdgcn_sched_barrier(0)
#define WLGKM \
    asm volatile("s_waitcnt lgkmcnt(0)" ::: "memory"); \
    __builtin_amdgcn_sched_barrier(0)

// Issue one 32-col half-tile (64 rows x 32 cols fp32 = 8 KB) via
// global_load_lds: instr i moves rows 8i..8i+7 of the half. LDS dest is
// linear (wave-uniform base + lane*16); the bank swizzle is applied on the
// per-lane GLOBAL source: quad position p in row r holds logical quad
// p ^ (r&7)  (both-sides rule: the read applies the same XOR).
#define ISSUE_HALF(XT, H)                                                   \
    {                                                                       \
        _Pragma("unroll") for (int i_ = 0; i_ < 8; ++i_) {                  \
            __builtin_amdgcn_global_load_lds(                               \
                (gfloat*)((XT) + gl_ld + i_ * 512 + (H) * 32),              \
                (sfloat*)(smw + (H) * 2048 + i_ * 256), 16, 0, 0);          \
        }                                                                   \
    }

#define FMACOL(XS, CIDX)                                                    \
    {                                                                       \
        const float* Wr2 = Wr + (CIDX) * 64;                                \
        _Pragma("unroll") for (int m_ = 0; m_ < 64; ++m_)                   \
            acc[m_] = fmaf(Wr2[m_], (XS), acc[m_]);                         \
    }

// Compute one half (32 iq columns): per q, one swizzled ds_read_b128 of the
// lane's own row quad, then 4x64 FMAs with wave-uniform (s_load) weights.
#define COMPUTE_HALF(H)                                                     \
    {                                                                       \
        _Pragma("unroll 2") for (int q_ = 0; q_ < 8; ++q_) {                \
            float4 xv = *(const float4*)(smw + (H) * 2048 + rd_b +          \
                                         ((q_ ^ lm7) << 2));                \
            const float* Wr = W + ((H) * 32 + 4 * q_) * 64;                 \
            FMACOL(xv.x, 0);                                                \
            FMACOL(xv.y, 1);                                                \
            FMACOL(xv.z, 2);                                                \
            FMACOL(xv.w, 3);                                                \
        }                                                                   \
    }

// Persistent waves; per wave two 8KB LDS half-buffers ping-ponged across
// tiles with counted vmcnt waits (never drained to 0 in steady state).
__global__ __launch_bounds__(256, 2) void clifford_main(
    const float* __restrict__ x, const float* __restrict__ W,
    const float* __restrict__ bias, float* __restrict__ out, int nB) {
    __shared__ __align__(16) float smem[4][4096];
    const int l = threadIdx.x & 63;
    const int wv = threadIdx.x >> 6;
    float* smw = smem[wv];
    const int nT = nB >> 6;
    const int nW = gridDim.x * 4;
    const int wid = blockIdx.x * 4 + wv;
    if (wid >= nT) return;

    const int lm7 = l & 7;
    const int gl_ld = (l >> 3) * 64 + ((lm7 ^ (l >> 3)) << 2);  // load src
    const int rd_b = l * 32;                  // own-row base within a half
    const int tr_rd = (l >> 3) * 32 + ((lm7 ^ (l >> 3)) << 2);  // out read
    const int st_of = (l >> 3) * 64 + (lm7 << 2);               // out store

    int t = wid;
    {
        const float* xt = x + (long long)t * 4096;
        ISSUE_HALF(xt, 0);
        ISSUE_HALF(xt, 1);
    }

    float acc[64];
    for (;;) {
        // ---- half 0 (buffer A) ----
#pragma unroll
        for (int m = 0; m < 64; ++m) acc[m] = bias[m];
        WAITVM8;  // A's 8 loads retired (B's 8 may stay in flight)
        COMPUTE_HALF(0);
        WLGKM;  // A's ds_reads landed in regs -> safe to overwrite A
        {
            int tn = t + nW;
            if (tn < nT) {
                const float* xn = x + (long long)tn * 4096;
                ISSUE_HALF(xn, 0);  // prefetch h0(t+nW) into A
            }
        }
        // ---- half 1 (buffer B) ----
        WAITVM8;  // stores+B retired (A's new 8 may stay in flight)
        COMPUTE_HALF(1);
        // ---- transpose + store via dead B ----
        {
            float* ot = out + (long long)t * 4096;
            float* Bf = smw + 2048;
#pragma unroll
            for (int mh = 0; mh < 2; ++mh) {
#pragma unroll
                for (int q = 0; q < 8; ++q) {
                    float4 v = make_float4(
                        acc[mh * 32 + 4 * q + 0], acc[mh * 32 + 4 * q + 1],
                        acc[mh * 32 + 4 * q + 2], acc[mh * 32 + 4 * q + 3]);
                    *(float4*)(Bf + rd_b + ((q ^ lm7) << 2)) = v;
                }
                // per-wave LDS ops retire in order: reads see the writes
#pragma unroll
                for (int i = 0; i < 8; ++i) {
                    float4 v = *(const float4*)(Bf + i * 256 + tr_rd);
                    *(float4*)(ot + i * 512 + st_of + mh * 32) = v;
                }
            }
        }
        WLGKM;  // transpose ds_reads consumed -> safe to overwrite B
        int tn = t + nW;
        if (tn >= nT) break;
        {
            const float* xn = x + (long long)tn * 4096;
            ISSUE_HALF(xn, 1);  // prefetch h1(t+nW) into B
        }
        t = tn;
    }
}

extern "C" void kernel_launch(void* const* d_in, const int* in_sizes, int n_in,
                              void* d_out, int out_size, void* d_ws,
                              size_t ws_size, hipStream_t stream) {
    const float* x = (const float*)d_in[0];
    const float* weight = (const float*)d_in[1];
    const float* bias = (const float*)d_in[2];
    float* out = (float*)d_out;
    float* W2 = (float*)d_ws;  // 4096 floats = 16 KB scratch

    int nB = in_sizes[0] / 64;  // 4096*512 batch elements

    hipLaunchKernelGGL(clifford_prep, dim3(1), dim3(256), 0, stream, weight,
                       W2);
    int nTiles = (nB + 63) / 64;
    int blocks = 512;  // 2 blocks/CU (LDS-capped), 2048 persistent waves
    if (blocks * 4 > nTiles) blocks = (nTiles + 3) / 4;
    hipLaunchKernelGGL(clifford_main, dim3(blocks), dim3(256), 0, stream, x,
                       W2, bias, out, nB);
}